// Round 4
// baseline (562.537 us; speedup 1.0000x reference)
//
#include <hip/hip_runtime.h>
#include <hip/hip_bf16.h>

#define D 128
#define K 32
#define NB 20000
#define NROWS 33            // 32 neighbours + 1 target node
#define RS 33               // LDS row stride in float4 (32 data + 1 pad)
#define RSF 132             // LDS row stride in floats

// ---------------------------------------------------------------------------
// Precompute (fp32): w1[d] = sum_e kernel1[d][e]*aw[e]
//                    w2[d] = sum_e kernel [d][e]*aw[128+e]
//                    MT[u][d] = sum_e kernel1[d][e]*nw[e][u]
// Grid: 65 blocks x 256 (blocks 0..63 -> MT, block 64 -> w1/w2).
// ---------------------------------------------------------------------------
__global__ __launch_bounds__(256)
void precompute_kernel(const float* __restrict__ k0,   // kernel   [D][D]
                       const float* __restrict__ k1,   // kernel1  [D][D]
                       const float* __restrict__ aw,   // [2D]
                       const float* __restrict__ nw,   // [D][D]
                       float* __restrict__ w1,
                       float* __restrict__ w2,
                       float* __restrict__ MT)          // [D][D], MT[u][d]
{
    int t = threadIdx.x;
    if (blockIdx.x < 64) {
        int gid = blockIdx.x * 256 + t;
        int u = gid >> 7, d = gid & 127;
        float acc = 0.f;
        #pragma unroll 8
        for (int e = 0; e < D; ++e)
            acc = fmaf(k1[d * D + e], nw[e * D + u], acc);
        MT[u * D + d] = acc;
    } else {
        if (t < 128) {
            float acc = 0.f;
            #pragma unroll 8
            for (int e = 0; e < D; ++e)
                acc = fmaf(k1[t * D + e], aw[e], acc);
            w1[t] = acc;
        } else {
            int d = t - 128;
            float acc = 0.f;
            #pragma unroll 8
            for (int e = 0; e < D; ++e)
                acc = fmaf(k0[d * D + e], aw[128 + e], acc);
            w2[d] = acc;
        }
    }
}

// ---------------------------------------------------------------------------
// Shared body: gather -> scores -> softmax -> aggregate (agg in LDS, fp32)
// ---------------------------------------------------------------------------
__device__ inline void gat_body(const float* features, const int* node,
                                const int* neigh, const float* w1, const float* w2,
                                int b, int t,
                                float4* fbuf, int* idxs, float (*psum)[8],
                                float* zb, float* alpha, float* agg)
{
    if (t < K)       idxs[t] = neigh[b * K + t];
    else if (t == K) idxs[K] = node[b];
    __syncthreads();

    // gather 33 rows x 512B in 16B chunks (coalesced per row)
    const float4* f4 = (const float4*)features;   // one feature row = 32 float4
    for (int c = t; c < NROWS * 32; c += 256) {
        int j = c >> 5, cc = c & 31;
        fbuf[j * RS + cc] = f4[(size_t)idxs[j] * 32 + cc];
    }
    __syncthreads();

    // partial dots: 33 rows x 8 chunks of 16 elems
    for (int task = t; task < NROWS * 8; task += 256) {
        int j = task >> 3, sub = task & 7;
        const float* w = (j < K) ? w1 : w2;
        const float4* r = &fbuf[j * RS + sub * 4];
        int d0 = sub * 16;
        float4 a0 = r[0], a1 = r[1], a2 = r[2], a3 = r[3];
        float acc;
        acc  = a0.x * w[d0 + 0]  + a0.y * w[d0 + 1]  + a0.z * w[d0 + 2]  + a0.w * w[d0 + 3];
        acc += a1.x * w[d0 + 4]  + a1.y * w[d0 + 5]  + a1.z * w[d0 + 6]  + a1.w * w[d0 + 7];
        acc += a2.x * w[d0 + 8]  + a2.y * w[d0 + 9]  + a2.z * w[d0 + 10] + a2.w * w[d0 + 11];
        acc += a3.x * w[d0 + 12] + a3.y * w[d0 + 13] + a3.z * w[d0 + 14] + a3.w * w[d0 + 15];
        psum[j][sub] = acc;
    }
    __syncthreads();

    if (t < NROWS) {
        float s = 0.f;
        #pragma unroll
        for (int i = 0; i < 8; ++i) s += psum[t][i];
        zb[t] = s;
    }
    __syncthreads();

    if (t == 0) {   // leaky-relu + softmax over K, serial (negligible)
        float c = zb[K];      // node-branch contribution, constant over k
        float m = -1e30f;
        #pragma unroll
        for (int k = 0; k < K; ++k) {
            float v = zb[k] + c;
            v = v > 0.f ? v : 0.2f * v;
            zb[k] = v;
            m = fmaxf(m, v);
        }
        float s = 0.f;
        #pragma unroll
        for (int k = 0; k < K; ++k) { float e = __expf(zb[k] - m); alpha[k] = e; s += e; }
        float inv = 1.f / s;
        #pragma unroll
        for (int k = 0; k < K; ++k) alpha[k] *= inv;
    }
    __syncthreads();

    // aggregate raw neighbor features: agg[d] = sum_k alpha[k]*f[k][d]
    const float* fb = (const float*)fbuf;
    if (t < D) {
        float a = 0.f;
        #pragma unroll
        for (int k = 0; k < K; ++k)
            a = fmaf(alpha[k], fb[k * RSF + t], a);
        agg[t] = a;
    }
    __syncthreads();
}

// ---------------------------------------------------------------------------
// Main kernel (ws path): epilogue via precomputed MT. fp32 in, fp32 out.
// ---------------------------------------------------------------------------
__global__ __launch_bounds__(256)
void gat_kernel(const float* __restrict__ features,   // [N_NODES][D]
                const int* __restrict__ node,         // [B]
                const int* __restrict__ neigh,        // [B][K]
                const float* __restrict__ w1g,
                const float* __restrict__ w2g,
                const float* __restrict__ MT,         // [D][D], MT[u][d]
                float* __restrict__ out)              // [B][D] fp32
{
    __shared__ float4 fbuf[NROWS * RS];
    __shared__ float w1[D], w2[D];
    __shared__ int   idxs[NROWS];
    __shared__ float psum[NROWS][8];
    __shared__ float zb[NROWS], alpha[K], agg[D];

    const int b = blockIdx.x, t = threadIdx.x;
    if (t < 128) w1[t] = w1g[t];
    else         w2[t - 128] = w2g[t - 128];

    gat_body(features, node, neigh, w1, w2, b, t, fbuf, idxs, psum, zb, alpha, agg);

    // out[b][u] = sum_d agg[d] * MT[u][d]
    if (t < D) {
        const float4* mt4 = (const float4*)(MT + t * D);
        float acc = 0.f;
        #pragma unroll 8
        for (int d4 = 0; d4 < D / 4; ++d4) {
            float4 m4 = mt4[d4];
            acc += agg[d4 * 4 + 0] * m4.x;
            acc += agg[d4 * 4 + 1] * m4.y;
            acc += agg[d4 * 4 + 2] * m4.z;
            acc += agg[d4 * 4 + 3] * m4.w;
        }
        out[(size_t)b * D + t] = acc;
    }
}

// ---------------------------------------------------------------------------
// Fallback (ws too small): recompute w1/w2 per block; epilogue streams
// kernel1 and neigh_weights from cache. Slower but scratch-free.
// ---------------------------------------------------------------------------
__global__ __launch_bounds__(256)
void gat_fallback_kernel(const float* __restrict__ features, const int* __restrict__ node,
                         const int* __restrict__ neigh,
                         const float* __restrict__ k0, const float* __restrict__ k1,
                         const float* __restrict__ aw, const float* __restrict__ nw,
                         float* __restrict__ out)
{
    __shared__ float4 fbuf[NROWS * RS];
    __shared__ float w1[D], w2[D], h[D];
    __shared__ int   idxs[NROWS];
    __shared__ float psum[NROWS][8];
    __shared__ float zb[NROWS], alpha[K], agg[D];

    const int b = blockIdx.x, t = threadIdx.x;

    if (t < 128) {
        float a = 0.f;
        for (int e = 0; e < D; ++e) a = fmaf(k1[t * D + e], aw[e], a);
        w1[t] = a;
    } else {
        int d = t - 128;
        float a = 0.f;
        for (int e = 0; e < D; ++e) a = fmaf(k0[d * D + e], aw[128 + e], a);
        w2[d] = a;
    }

    gat_body(features, node, neigh, w1, w2, b, t, fbuf, idxs, psum, zb, alpha, agg);

    if (t < 128) {          // h[e] = sum_d agg[d] * k1[d][e]
        float acc = 0.f;
        for (int d = 0; d < D; ++d) acc = fmaf(agg[d], k1[d * D + t], acc);
        h[t] = acc;
    }
    __syncthreads();
    if (t < 128) {          // out[u] = sum_e h[e] * nw[e][u]
        float acc = 0.f;
        for (int e = 0; e < D; ++e) acc = fmaf(h[e], nw[e * D + t], acc);
        out[(size_t)b * D + t] = acc;
    }
}

extern "C" void kernel_launch(void* const* d_in, const int* in_sizes, int n_in,
                              void* d_out, int out_size, void* d_ws, size_t ws_size,
                              hipStream_t stream) {
    const float* features = (const float*)d_in[0];
    const int*   node     = (const int*)d_in[1];
    const int*   neigh    = (const int*)d_in[2];
    const float* k0       = (const float*)d_in[3];
    const float* k1       = (const float*)d_in[4];
    const float* aw       = (const float*)d_in[5];
    const float* nw       = (const float*)d_in[6];

    const size_t need = (size_t)(2 * D + D * D) * sizeof(float);   // 66.5 KB
    if (ws_size >= need) {
        float* w1 = (float*)d_ws;
        float* w2 = w1 + D;
        float* MT = w2 + D;
        precompute_kernel<<<65, 256, 0, stream>>>(k0, k1, aw, nw, w1, w2, MT);
        gat_kernel<<<NB, 256, 0, stream>>>(features, node, neigh, w1, w2, MT,
                                           (float*)d_out);
    } else {
        gat_fallback_kernel<<<NB, 256, 0, stream>>>(features, node, neigh,
                                                    k0, k1, aw, nw, (float*)d_out);
    }
}

// Round 5
// 413.433 us; speedup vs baseline: 1.3606x; 1.3606x over previous
//
#include <hip/hip_runtime.h>
#include <hip/hip_bf16.h>

#define D 128
#define K 32
#define NB 20000
#define NPB 4                 // nodes per block
#define NBLK (NB / NPB)       // 5000 blocks
#define NROWS 33              // per node: 32 neighbours + 1 target
#define RSTRIDE 66            // fbuf row stride in dwords (132 bf16; 64 used + pad)

typedef unsigned short u16;
typedef unsigned int   u32;

__device__ inline float blo(u32 v) { return __uint_as_float(v << 16); }
__device__ inline float bhi(u32 v) { return __uint_as_float(v & 0xffff0000u); }
__device__ inline u32 f2b_rne(float x) {           // fp32 -> bf16 (round-nearest-even)
    u32 u = __float_as_uint(x);
    return (u + 0x7fffu + ((u >> 16) & 1u)) >> 16;
}
__device__ inline u32 pack2(float a, float b) { return f2b_rne(a) | (f2b_rne(b) << 16); }

// ---------------------------------------------------------------------------
// Precompute: w12[0..127] = kernel1 @ aw[0:128]   (score vec for neighbours)
//             w12[128..255] = kernel @ aw[128:256] (score vec for node)
//             MTb[u][d] = sum_e kernel1[d][e]*nw[e][u], stored bf16
// blocks 0..63 -> MTb (u thread-fast: nw coalesced, k1 broadcast); block 64 -> w12.
// ---------------------------------------------------------------------------
__global__ __launch_bounds__(256)
void precompute_kernel(const float* __restrict__ k0, const float* __restrict__ k1,
                       const float* __restrict__ aw, const float* __restrict__ nw,
                       float* __restrict__ w12, u16* __restrict__ MTb)
{
    int t = threadIdx.x;
    if (blockIdx.x < 64) {
        int gid = blockIdx.x * 256 + t;
        int u = gid & 127, d = gid >> 7;
        float acc = 0.f;
        #pragma unroll 8
        for (int e = 0; e < D; ++e)
            acc = fmaf(k1[d * D + e], nw[e * D + u], acc);
        MTb[u * D + d] = (u16)f2b_rne(acc);
    } else {
        if (t < 128) {
            float acc = 0.f;
            #pragma unroll 8
            for (int e = 0; e < D; ++e)
                acc = fmaf(k1[t * D + e], aw[e], acc);
            w12[t] = acc;
        } else {
            int d = t - 128;
            float acc = 0.f;
            #pragma unroll 8
            for (int e = 0; e < D; ++e)
                acc = fmaf(k0[d * D + e], aw[128 + e], acc);
            w12[t] = acc;
        }
    }
}

// ---------------------------------------------------------------------------
// Main kernel: 4 nodes per 256-thread block.
// Row index r = 4*j + n (node n, row j; j==32 is the target-node row).
// Phases: P0 idx/w | P1 gather+score (shfl-reduced, fp32-exact) | P2 softmax
//         P3 aggregate (bf16 rows) | P4 epilogue via bf16 MT.  4 barriers.
// ---------------------------------------------------------------------------
__global__ __launch_bounds__(256)
void gat4_kernel(const float* __restrict__ features,
                 const int* __restrict__ node,
                 const int* __restrict__ neigh,
                 const float* __restrict__ w12g,   // [256]
                 const u16* __restrict__ MTb,      // [D][D] bf16, MTb[u][d]
                 float* __restrict__ out)          // [NB][D] fp32
{
    __shared__ u32   fbuf[132 * RSTRIDE];  // 34.8 KB: 132 rows x 128 bf16 (+pad)
    __shared__ float wlds[256];
    __shared__ int   idxs[132];            // [r]
    __shared__ float zb[132];              // [n*33+j]
    __shared__ float alpha[128];           // [n*32+k]
    __shared__ float agg[512];             // [n*128+d]

    const int t  = threadIdx.x;
    const int b4 = blockIdx.x * NPB;

    // P0: indices + score weight vectors
    wlds[t] = w12g[t];
    if (t < 132) {
        int n = t & 3, j = t >> 2;
        idxs[t] = (j < K) ? neigh[(b4 + n) * K + j] : node[b4 + n];
    }
    __syncthreads();

    // P1: gather rows (fp32 global -> bf16 LDS) + fused score partials.
    // Each iteration: one half-wave (32 lanes) covers one full row; shfl-reduce
    // gives the exact fp32 score, written by lane cc==0. No atomics, no extra phase.
    const float4* f4 = (const float4*)features;
    #pragma unroll 4
    for (int c = t; c < 132 * 32; c += 256) {
        int r = c >> 5, cc = c & 31;
        float4 v = f4[(size_t)idxs[r] * 32 + cc];
        u32* dst = &fbuf[r * RSTRIDE + cc * 2];
        dst[0] = pack2(v.x, v.y);
        dst[1] = pack2(v.z, v.w);
        const float* w = &wlds[((r < 128) ? 0 : 128) + cc * 4];
        float p = v.x * w[0] + v.y * w[1] + v.z * w[2] + v.w * w[3];
        p += __shfl_xor(p, 1);
        p += __shfl_xor(p, 2);
        p += __shfl_xor(p, 4);
        p += __shfl_xor(p, 8);
        p += __shfl_xor(p, 16);
        if (cc == 0) zb[(r & 3) * 33 + (r >> 2)] = p;
    }
    __syncthreads();

    // P2: leaky-relu + softmax, one lane per node (4 in parallel, one per wave)
    if ((t & 63) == 0) {
        int n = t >> 6;
        float cadd = zb[n * 33 + 32];
        float m = -1e30f;
        #pragma unroll
        for (int k = 0; k < K; ++k) {
            float v = zb[n * 33 + k] + cadd;
            v = v > 0.f ? v : 0.2f * v;
            alpha[n * 32 + k] = v;
            m = fmaxf(m, v);
        }
        float s = 0.f;
        #pragma unroll
        for (int k = 0; k < K; ++k) {
            float e = __expf(alpha[n * 32 + k] - m);
            alpha[n * 32 + k] = e;
            s += e;
        }
        float inv = 1.f / s;
        #pragma unroll
        for (int k = 0; k < K; ++k) alpha[n * 32 + k] *= inv;
    }
    __syncthreads();

    // P3: aggregate: agg[n][d] = sum_k alpha[n][k] * f[n][k][d]  (bf16 rows)
    {
        int n = t >> 6, p = t & 63;           // wave n handles node n; p = dword
        float a0 = 0.f, a1 = 0.f;
        #pragma unroll
        for (int k = 0; k < K; ++k) {
            u32 v = fbuf[(4 * k + n) * RSTRIDE + p];
            float al = alpha[n * 32 + k];     // wave-uniform broadcast
            a0 = fmaf(al, blo(v), a0);
            a1 = fmaf(al, bhi(v), a1);
        }
        agg[n * 128 + 2 * p]     = a0;
        agg[n * 128 + 2 * p + 1] = a1;
    }
    __syncthreads();

    // P4: out[n][u] = sum_d agg[n][d] * MT[u][d]; thread t covers (nA,u),(nA+2,u)
    {
        int u  = t & 127;
        int nA = t >> 7;                      // 0 or 1
        const uint4* mrow = (const uint4*)(MTb + u * D);   // 16 x (8 bf16)
        const float* aggA = &agg[nA * 128];
        const float* aggB = &agg[(nA + 2) * 128];
        float accA0 = 0.f, accA1 = 0.f, accB0 = 0.f, accB1 = 0.f;
        #pragma unroll
        for (int q = 0; q < 16; ++q) {
            uint4 m4 = mrow[q];
            int d0 = q * 8;
            float m0 = blo(m4.x), m1 = bhi(m4.x), m2 = blo(m4.y), m3 = bhi(m4.y);
            float m4f = blo(m4.z), m5 = bhi(m4.z), m6 = blo(m4.w), m7 = bhi(m4.w);
            accA0 += aggA[d0] * m0 + aggA[d0+1] * m1 + aggA[d0+2] * m2 + aggA[d0+3] * m3;
            accA1 += aggA[d0+4] * m4f + aggA[d0+5] * m5 + aggA[d0+6] * m6 + aggA[d0+7] * m7;
            accB0 += aggB[d0] * m0 + aggB[d0+1] * m1 + aggB[d0+2] * m2 + aggB[d0+3] * m3;
            accB1 += aggB[d0+4] * m4f + aggB[d0+5] * m5 + aggB[d0+6] * m6 + aggB[d0+7] * m7;
        }
        out[(size_t)(b4 + nA) * D + u]     = accA0 + accA1;
        out[(size_t)(b4 + nA + 2) * D + u] = accB0 + accB1;
    }
}

// ---------------------------------------------------------------------------
// Fallback (ws too small): round-4 known-good fp32 path, scratch-free.
// ---------------------------------------------------------------------------
#define RS 33
#define RSF 132
__global__ __launch_bounds__(256)
void gat_fallback_kernel(const float* __restrict__ features, const int* __restrict__ node,
                         const int* __restrict__ neigh,
                         const float* __restrict__ k0, const float* __restrict__ k1,
                         const float* __restrict__ aw, const float* __restrict__ nw,
                         float* __restrict__ out)
{
    __shared__ float4 fbuf[NROWS * RS];
    __shared__ float w1[D], w2[D], h[D];
    __shared__ int   idxs[NROWS];
    __shared__ float psum[NROWS][8];
    __shared__ float zb[NROWS], alpha[K], agg[D];

    const int b = blockIdx.x, t = threadIdx.x;

    if (t < 128) {
        float a = 0.f;
        for (int e = 0; e < D; ++e) a = fmaf(k1[t * D + e], aw[e], a);
        w1[t] = a;
    } else {
        int d = t - 128;
        float a = 0.f;
        for (int e = 0; e < D; ++e) a = fmaf(k0[d * D + e], aw[128 + e], a);
        w2[d] = a;
    }
    if (t < K)       idxs[t] = neigh[b * K + t];
    else if (t == K) idxs[K] = node[b];
    __syncthreads();

    const float4* f4 = (const float4*)features;
    for (int c = t; c < NROWS * 32; c += 256) {
        int j = c >> 5, cc = c & 31;
        fbuf[j * RS + cc] = f4[(size_t)idxs[j] * 32 + cc];
    }
    __syncthreads();

    for (int task = t; task < NROWS * 8; task += 256) {
        int j = task >> 3, sub = task & 7;
        const float* w = (j < K) ? w1 : w2;
        const float4* r = &fbuf[j * RS + sub * 4];
        int d0 = sub * 16;
        float4 a0 = r[0], a1 = r[1], a2 = r[2], a3 = r[3];
        float acc;
        acc  = a0.x * w[d0 + 0]  + a0.y * w[d0 + 1]  + a0.z * w[d0 + 2]  + a0.w * w[d0 + 3];
        acc += a1.x * w[d0 + 4]  + a1.y * w[d0 + 5]  + a1.z * w[d0 + 6]  + a1.w * w[d0 + 7];
        acc += a2.x * w[d0 + 8]  + a2.y * w[d0 + 9]  + a2.z * w[d0 + 10] + a2.w * w[d0 + 11];
        acc += a3.x * w[d0 + 12] + a3.y * w[d0 + 13] + a3.z * w[d0 + 14] + a3.w * w[d0 + 15];
        psum[j][sub] = acc;
    }
    __syncthreads();

    if (t < NROWS) {
        float s = 0.f;
        #pragma unroll
        for (int i = 0; i < 8; ++i) s += psum[t][i];
        zb[t] = s;
    }
    __syncthreads();

    if (t == 0) {
        float c = zb[K];
        float m = -1e30f;
        #pragma unroll
        for (int k = 0; k < K; ++k) {
            float v = zb[k] + c;
            v = v > 0.f ? v : 0.2f * v;
            zb[k] = v;
            m = fmaxf(m, v);
        }
        float s = 0.f;
        #pragma unroll
        for (int k = 0; k < K; ++k) { float e = __expf(zb[k] - m); alpha[k] = e; s += e; }
        float inv = 1.f / s;
        #pragma unroll
        for (int k = 0; k < K; ++k) alpha[k] *= inv;
    }
    __syncthreads();

    const float* fb = (const float*)fbuf;
    if (t < D) {
        float a = 0.f;
        #pragma unroll
        for (int k = 0; k < K; ++k)
            a = fmaf(alpha[k], fb[k * RSF + t], a);
        agg[t] = a;
    }
    __syncthreads();

    if (t < 128) {
        float acc = 0.f;
        for (int d = 0; d < D; ++d) acc = fmaf(agg[d], k1[d * D + t], acc);
        h[t] = acc;
    }
    __syncthreads();
    if (t < 128) {
        float acc = 0.f;
        for (int e = 0; e < D; ++e) acc = fmaf(h[e], nw[e * D + t], acc);
        out[(size_t)b * D + t] = acc;
    }
}

extern "C" void kernel_launch(void* const* d_in, const int* in_sizes, int n_in,
                              void* d_out, int out_size, void* d_ws, size_t ws_size,
                              hipStream_t stream) {
    const float* features = (const float*)d_in[0];
    const int*   node     = (const int*)d_in[1];
    const int*   neigh    = (const int*)d_in[2];
    const float* k0       = (const float*)d_in[3];
    const float* k1       = (const float*)d_in[4];
    const float* aw       = (const float*)d_in[5];
    const float* nw       = (const float*)d_in[6];

    // ws layout: w12 (256 f32, 1 KB) | MTb (128*128 bf16, 32 KB)
    const size_t need = 256 * sizeof(float) + (size_t)D * D * sizeof(u16);
    if (ws_size >= need) {
        float* w12 = (float*)d_ws;
        u16*   MTb = (u16*)(w12 + 256);
        precompute_kernel<<<65, 256, 0, stream>>>(k0, k1, aw, nw, w12, MTb);
        gat4_kernel<<<NBLK, 256, 0, stream>>>(features, node, neigh, w12, MTb,
                                              (float*)d_out);
    } else {
        gat_fallback_kernel<<<NB, 256, 0, stream>>>(features, node, neigh,
                                                    k0, k1, aw, nw, (float*)d_out);
    }
}